// Round 6
// baseline (501.414 us; speedup 1.0000x reference)
//
#include <hip/hip_runtime.h>
#include <hip/hip_bf16.h>

typedef unsigned int u32;
typedef unsigned short u16;
typedef unsigned char u8;

#define NN 50000
#define EE 800000
#define TT 3
#define NBUCK 196        // dst>>8 buckets
#define BSTRIDE 8192     // fixed stride per bucket in TMP (max bucket ~4400)
#define P1_CHUNK 4096

// ws layout (dword offsets) — total 8,953,024 dwords = 35.8 MiB
#define OFF_C1     0         // 1536 f
#define OFF_C2     1536      // 192 f
#define OFF_BCNT   1728      // 256 i (memset-zeroed) — bucket cursors/counts
#define OFF_OPART  1984      // 1024 f (memset-zeroed)
#define OFF_BBASE  3008      // 256 i — bucket base offsets (written by sort_p2a)
#define OFF_ROWPTR 52756     // 50004 i (written by sort_p2/p2a)
#define OFF_CW1    102760    // 14336 f: folded layer-0 weights [64 k][224 c]
#define OFF_CW2    117096    // 4352 f: folded layer-1 weights [64 k][68 c]
#define OFF_PSRC   153016    // 800000 i (src | etype<<20, dst-sorted)
#define OFF_PK1    953024    // N*3 rows * 32 dw: [16 dw fp8 F][4 dw bf16 EP][12 pad]
#define OFF_TMP    953024    // overlays PK1 (dead until gemm_f): NBUCK*BSTRIDE = 1,605,632 i
#define OFF_PK2    953024    // overlays PK1 (dead after agg1): N*3 rows * 16 dw: [8 dw bf16 F2][EG f32][7 pad]
#define OFF_H      5753024   // N*64 f = 3,200,000
// memset range: dword 1728 .. 3007 (BCNT+OPART) = 1280 dwords

__device__ __forceinline__ float bf2f(u32 u) {
    union { u32 i; float f; } v; v.i = u << 16; return v.f;
}
__device__ __forceinline__ u32 f2bf(float f) {  // RNE
    union { float f; u32 i; } v; v.f = f;
    return (v.i + 0x7fffu + ((v.i >> 16) & 1u)) >> 16;
}

// C1[t][k][h] = sum_k2 W1[t][k][k2] * sum_j (al1+ar1)[t][k2][h*8+j]
// c2[t][k]   = sum_k2 W2[t][k][k2] * sum_j (al2+ar2)[t][k2][j]
__global__ void precompute(const float* __restrict__ W1, const float* __restrict__ al1,
                           const float* __restrict__ ar1, const float* __restrict__ W2,
                           const float* __restrict__ al2, const float* __restrict__ ar2,
                           float* __restrict__ ws) {
    __shared__ float a1c[64][8];
    __shared__ float a2c[16];
    int t = blockIdx.x;
    int tid = threadIdx.x;
    {
        int k2 = tid >> 3, hh = tid & 7;
        float s = 0.f;
#pragma unroll
        for (int j = 0; j < 8; ++j) {
            int idx = t * 4096 + k2 * 64 + hh * 8 + j;
            s += al1[idx] + ar1[idx];
        }
        a1c[k2][hh] = s;
    }
    if (tid < 16) {
        float s = 0.f;
#pragma unroll
        for (int j = 0; j < 16; ++j) {
            int idx = t * 256 + tid * 16 + j;
            s += al2[idx] + ar2[idx];
        }
        a2c[tid] = s;
    }
    __syncthreads();
    {
        int k = tid >> 3, hh = tid & 7;
        float s = 0.f;
#pragma unroll
        for (int k2 = 0; k2 < 64; ++k2)
            s += W1[t * 4096 + k * 64 + k2] * a1c[k2][hh];
        ws[OFF_C1 + t * 512 + k * 8 + hh] = s;
    }
    if (tid < 64) {
        float s = 0.f;
#pragma unroll
        for (int k2 = 0; k2 < 16; ++k2)
            s += W2[t * 1024 + tid * 16 + k2] * a2c[k2];
        ws[OFF_C2 + t * 64 + tid] = s;
    }
}

// Stage folded weights into global.
// CW1[k][c]: c<192 -> W1[t=c>>6][k][c&63]; 192..215 -> C1; 216..223 -> 0.
// CW2[k][c]: c<48 -> W2[t=c>>4][k][c&15]; 48..50 -> C2; 51..66 -> res_w; 67 -> 0.
__global__ __launch_bounds__(256) void fill_cw(const float* __restrict__ W1, const float* __restrict__ W2,
                        const float* __restrict__ res_w, float* __restrict__ ws) {
    int idx = blockIdx.x * 256 + threadIdx.x;
    if (idx < 14336) {
        int k = idx / 224, c = idx - k * 224;
        float v;
        if (c < 192) v = W1[(c >> 6) * 4096 + k * 64 + (c & 63)];
        else if (c < 216) v = ws[OFF_C1 + ((c - 192) >> 3) * 512 + k * 8 + ((c - 192) & 7)];
        else v = 0.f;
        ws[OFF_CW1 + idx] = v;
    }
    if (idx < 4352) {
        int k = idx / 68, c = idx - k * 68;
        float v;
        if (c < 48) v = W2[(c >> 4) * 1024 + k * 16 + (c & 15)];
        else if (c < 51) v = ws[OFF_C2 + (c - 48) * 64 + k];
        else if (c < 67) v = res_w[k * 16 + (c - 51)];
        else v = 0.f;
        ws[OFF_CW2 + idx] = v;
    }
}

// sort pass 1: bucket edges by dst>>8 into fixed-stride TMP regions.
// entry = src[15:0] | etype<<16 [17:16] | (dst&255)<<18 [25:18]
__global__ __launch_bounds__(256) void sort_p1(const int* __restrict__ src, const int* __restrict__ dst,
                        const int* __restrict__ etype, int* wsi) {
    __shared__ u32 Est[P1_CHUNK];
    __shared__ u8 Bst[P1_CHUNK];
    __shared__ int hist[NBUCK], base[NBUCK];
    int tid = threadIdx.x;
    int e0 = blockIdx.x * P1_CHUNK;
    int cnt = EE - e0; if (cnt > P1_CHUNK) cnt = P1_CHUNK;
    for (int i = tid; i < NBUCK; i += 256) hist[i] = 0;
    __syncthreads();
    for (int i = tid; i < cnt; i += 256) {
        int e = e0 + i;
        int s = src[e], d = dst[e], t = etype[e];
        int b = d >> 8;
        Est[i] = (u32)s | ((u32)t << 16) | ((u32)(d & 255) << 18);
        Bst[i] = (u8)b;
        atomicAdd(&hist[b], 1);
    }
    __syncthreads();
    for (int i = tid; i < NBUCK; i += 256) {
        int h = hist[i];
        base[i] = h ? atomicAdd(wsi + OFF_BCNT + i, h) : 0;
        hist[i] = 0;
    }
    __syncthreads();
    for (int i = tid; i < cnt; i += 256) {
        int b = Bst[i];
        int idx = base[b] + atomicAdd(&hist[b], 1);
        wsi[OFF_TMP + b * BSTRIDE + idx] = (int)Est[i];
    }
}

// sort pass 2a: exclusive scan of bucket counts -> BBASE; rowptr[NN] = EE.
__global__ __launch_bounds__(256) void sort_p2a(int* wsi) {
    __shared__ int sd[256];
    int t = threadIdx.x;
    int v = (t < NBUCK) ? wsi[OFF_BCNT + t] : 0;
    sd[t] = v;
    __syncthreads();
    for (int o = 1; o < 256; o <<= 1) {
        int u = (t >= o) ? sd[t - o] : 0;
        __syncthreads();
        sd[t] += u;
        __syncthreads();
    }
    if (t < NBUCK) wsi[OFF_BBASE + t] = sd[t] - v;  // exclusive
    if (t == 0) wsi[OFF_ROWPTR + NN] = EE;
}

// sort pass 2: per bucket, count per-dst in LDS, scan -> rowptr, scatter into
// final psrc window (16 KB, L2-resident). psrc format: src | etype<<20.
__global__ __launch_bounds__(256) void sort_p2(int* wsi) {
    __shared__ int cnt[256], sd[256], lrpx[256];
    int b = blockIdx.x;
    int tid = threadIdx.x;
    int nb = wsi[OFF_BCNT + b];
    int gbase = wsi[OFF_BBASE + b];
    cnt[tid] = 0;
    __syncthreads();
    const int* tmp = wsi + OFF_TMP + b * BSTRIDE;
    for (int i = tid; i < nb; i += 256) {
        int e = tmp[i];
        atomicAdd(&cnt[(e >> 18) & 255], 1);
    }
    __syncthreads();
    int v = cnt[tid];
    sd[tid] = v;
    __syncthreads();
    for (int o = 1; o < 256; o <<= 1) {
        int u = (tid >= o) ? sd[tid - o] : 0;
        __syncthreads();
        sd[tid] += u;
        __syncthreads();
    }
    int ex = sd[tid] - v;  // exclusive prefix within bucket
    lrpx[tid] = ex;
    int d = b * 256 + tid;
    if (d < NN) wsi[OFF_ROWPTR + d] = gbase + ex;
    cnt[tid] = 0;
    __syncthreads();
    for (int i = tid; i < nb; i += 256) {
        int e = tmp[i];
        int dres = (e >> 18) & 255;
        int slot = gbase + lrpx[dres] + atomicAdd(&cnt[dres], 1);
        wsi[OFF_PSRC + slot] = (e & 0xFFFF) | (((e >> 16) & 3) << 20);
    }
}

// PK1[n][t] row (32 dw): F fp8 (dw 0-15) + EP bf16 (dw 16-19).
// 8 waves; wave = 28-col slice (weights wave-uniform -> SGPRs via s_load),
// lane = node; x row in VGPRs. Needs ~110 VGPR: amdgpu_waves_per_eu(2)
// raises the allocator budget to 256 (r4: cap 64 spilled; r5: scheduler's
// own target capped at 80 and spilled ~25 dw/thread -> 48 MB WRITE_SIZE).
__global__ __launch_bounds__(512) __attribute__((amdgpu_waves_per_eu(2)))
void gemm_f(const float* __restrict__ x, const float* __restrict__ cw,
            float* __restrict__ ws) {
    int tid = threadIdx.x;
    int wave = __builtin_amdgcn_readfirstlane(tid >> 6);
    int lane = tid & 63;
    int n0 = blockIdx.x * 64;
    int n = n0 + lane;
    float xr[64];
#pragma unroll
    for (int i = 0; i < 16; ++i)
        *(float4*)(xr + 4 * i) = make_float4(0.f, 0.f, 0.f, 0.f);
    if (n < NN) {
        const float4* xg = (const float4*)(x + (size_t)n * 64);
#pragma unroll
        for (int i = 0; i < 16; ++i)
            *(float4*)(xr + 4 * i) = xg[i];
    }
    int cbase = wave * 28;
    float acc[28];
#pragma unroll
    for (int i = 0; i < 28; ++i) acc[i] = 0.f;
    float wA[28], wB[28];
#pragma unroll
    for (int j = 0; j < 28; ++j) wA[j] = cw[cbase + j];
#pragma unroll
    for (int k = 0; k < 64; k += 2) {
#pragma unroll
        for (int j = 0; j < 28; ++j) wB[j] = cw[(k + 1) * 224 + cbase + j];
        float xv = xr[k];
#pragma unroll
        for (int j = 0; j < 28; ++j) acc[j] = fmaf(xv, wA[j], acc[j]);
        if (k + 2 < 64) {
#pragma unroll
            for (int j = 0; j < 28; ++j) wA[j] = cw[(k + 2) * 224 + cbase + j];
        }
        float xv2 = xr[k + 1];
#pragma unroll
        for (int j = 0; j < 28; ++j) acc[j] = fmaf(xv2, wB[j], acc[j]);
    }
    if (n < NN) {
        u32* row = (u32*)ws + OFF_PK1 + (size_t)n * 96;
#pragma unroll
        for (int g = 0; g < 7; ++g) {
            int col = cbase + 4 * g;
            float v0 = acc[4*g], v1 = acc[4*g+1], v2 = acc[4*g+2], v3 = acc[4*g+3];
            if (col < 192) {
                int t = col >> 6, ci = col & 63;
                int dw = __builtin_amdgcn_cvt_pk_fp8_f32(v0, v1, 0, false);
                dw = __builtin_amdgcn_cvt_pk_fp8_f32(v2, v3, dw, true);
                row[t * 32 + (ci >> 2)] = (u32)dw;
            } else if (col < 216) {
                int jj = col - 192;
                int t = jj >> 3, rem = jj & 7;  // rem in {0,4}
                v0 = v0 > 0.f ? v0 : 0.2f * v0;
                v1 = v1 > 0.f ? v1 : 0.2f * v1;
                v2 = v2 > 0.f ? v2 : 0.2f * v2;
                v3 = v3 > 0.f ? v3 : 0.2f * v3;
                row[t * 32 + 16 + (rem >> 1)]     = f2bf(__expf(v0)) | (f2bf(__expf(v1)) << 16);
                row[t * 32 + 16 + (rem >> 1) + 1] = f2bf(__expf(v2)) | (f2bf(__expf(v3)) << 16);
            }
        }
    }
}

// layer0 fused softmax+aggregate — 4-way edge-parallel per wave.
__global__ __launch_bounds__(256) void agg1(const int* __restrict__ wsi, float* __restrict__ ws) {
    int tid = threadIdx.x;
    int wave = tid >> 6, lane = tid & 63;
    int q = lane >> 4;
    int cg = lane & 15;
    int d = blockIdx.x * 4 + wave;
    int epw = cg >> 2;
    int sh_ep = ((cg >> 1) & 1) * 16;
    int start = wsi[OFF_ROWPTR + d], end = wsi[OFF_ROWPTR + d + 1];
    const u32* pk = (const u32*)ws + OFF_PK1;
    const int* psrc = wsi + OFF_PSRC;
    float acc0 = 0.f, acc1 = 0.f, acc2 = 0.f, acc3 = 0.f, den = 0.f;
    int s = start + q;
    u32 fdw_c = 0, epdw_c = 0;
    int p1 = 0;
    bool valid = s < end;
    if (valid) {
        int p = psrc[s];
        int sn = p & 0xFFFFF, t = p >> 20;
        size_t base = (size_t)(sn * 3 + t) * 32;
        fdw_c = pk[base + cg];
        epdw_c = pk[base + 16 + epw];
    }
    if (s + 4 < end) p1 = psrc[s + 4];
    while (valid) {
        u32 fdw = fdw_c, epdw = epdw_c;
        bool v1 = s + 4 < end;
        if (v1) {
            int sn = p1 & 0xFFFFF, t = p1 >> 20;
            size_t base = (size_t)(sn * 3 + t) * 32;
            fdw_c = pk[base + cg];
            epdw_c = pk[base + 16 + epw];
        }
        if (s + 8 < end) p1 = psrc[s + 8];
        float w = bf2f((epdw >> sh_ep) & 0xffffu);
        float m0 = __builtin_amdgcn_cvt_f32_fp8((int)fdw, 0);
        float m1 = __builtin_amdgcn_cvt_f32_fp8((int)(fdw >> 8), 0);
        float m2 = __builtin_amdgcn_cvt_f32_fp8((int)(fdw >> 16), 0);
        float m3 = __builtin_amdgcn_cvt_f32_fp8((int)(fdw >> 24), 0);
        den += w;
        acc0 += w * m0;
        acc1 += w * m1;
        acc2 += w * m2;
        acc3 += w * m3;
        s += 4;
        valid = v1;
    }
    acc0 += __shfl_xor(acc0, 16); acc0 += __shfl_xor(acc0, 32);
    acc1 += __shfl_xor(acc1, 16); acc1 += __shfl_xor(acc1, 32);
    acc2 += __shfl_xor(acc2, 16); acc2 += __shfl_xor(acc2, 32);
    acc3 += __shfl_xor(acc3, 16); acc3 += __shfl_xor(acc3, 32);
    den  += __shfl_xor(den, 16);  den  += __shfl_xor(den, 32);
    if (q == 0) {
        float dn = (end > start) ? den : 1.f;
        float v0 = acc0 / dn, v1 = acc1 / dn, v2 = acc2 / dn, v3 = acc3 / dn;
        v0 = v0 > 0.f ? v0 : __expf(v0) - 1.f;  // ELU
        v1 = v1 > 0.f ? v1 : __expf(v1) - 1.f;
        v2 = v2 > 0.f ? v2 : __expf(v2) - 1.f;
        v3 = v3 > 0.f ? v3 : __expf(v3) - 1.f;
        *(float4*)(ws + OFF_H + (size_t)d * 64 + cg * 4) = make_float4(v0, v1, v2, v3);
    }
}

// PK2[n][t] = [16 bf16 F2][EG f32]; residual partials to OPART.
// 4 waves; wave = 17-col slice, lane = node; H row in VGPRs (~95 VGPR).
__global__ __launch_bounds__(256) __attribute__((amdgpu_waves_per_eu(2)))
void gemm_f2(const float* __restrict__ cw, float* __restrict__ ws) {
    __shared__ float Rs[64][17];
    int tid = threadIdx.x;
    int wave = __builtin_amdgcn_readfirstlane(tid >> 6);
    int lane = tid & 63;
    int n0 = blockIdx.x * 64;
    int n = n0 + lane;
    float hr[64];
#pragma unroll
    for (int i = 0; i < 16; ++i)
        *(float4*)(hr + 4 * i) = make_float4(0.f, 0.f, 0.f, 0.f);
    if (n < NN) {
        const float4* hg = (const float4*)(ws + OFF_H + (size_t)n * 64);
#pragma unroll
        for (int i = 0; i < 16; ++i)
            *(float4*)(hr + 4 * i) = hg[i];
    }
    int cbase = wave * 17;
    float acc[17];
#pragma unroll
    for (int i = 0; i < 17; ++i) acc[i] = 0.f;
    float wA[17], wB[17];
#pragma unroll
    for (int j = 0; j < 17; ++j) wA[j] = cw[cbase + j];
#pragma unroll
    for (int k = 0; k < 64; k += 2) {
#pragma unroll
        for (int j = 0; j < 17; ++j) wB[j] = cw[(k + 1) * 68 + cbase + j];
        float hv = hr[k];
#pragma unroll
        for (int j = 0; j < 17; ++j) acc[j] = fmaf(hv, wA[j], acc[j]);
        if (k + 2 < 64) {
#pragma unroll
            for (int j = 0; j < 17; ++j) wA[j] = cw[(k + 2) * 68 + cbase + j];
        }
        float hv2 = hr[k + 1];
#pragma unroll
        for (int j = 0; j < 17; ++j) acc[j] = fmaf(hv2, wB[j], acc[j]);
    }
    u16* pk2u = (u16*)((u32*)ws + OFF_PK2);
#pragma unroll
    for (int i = 0; i < 17; ++i) {
        int col = cbase + i;
        if (col < 48) {
            if (n < NN) {
                int t = col >> 4, c2 = col & 15;
                pk2u[((size_t)n * 3 + t) * 32 + c2] = (u16)f2bf(acc[i]);
            }
        } else if (col < 51) {
            if (n < NN) {
                float v = acc[i]; v = v > 0.f ? v : 0.2f * v;
                ws[OFF_PK2 + ((size_t)n * 3 + (col - 48)) * 16 + 8] = __expf(v);
            }
        } else if (col < 67) {
            Rs[lane][col - 51] = acc[i];
        }
    }
    __syncthreads();
    if (tid < 16) {
        float s = 0.f;
#pragma unroll 8
        for (int r = 0; r < 64; ++r) s += Rs[r][tid];
        atomicAdd(ws + OFF_OPART + (blockIdx.x & 63) * 16 + tid, s);
    }
}

// layer1 fused — PK2 single-line gathers.
__global__ __launch_bounds__(256) void agg2(const int* __restrict__ wsi, float* __restrict__ ws) {
    __shared__ float outs[4][16];
    int tid = threadIdx.x;
    int wave = tid >> 6, lane = tid & 63;
    int q = lane >> 4, c = lane & 15;
    int d = blockIdx.x * 4 + wave;
    int start = wsi[OFF_ROWPTR + d], end = wsi[OFF_ROWPTR + d + 1];
    const u16* pk2u = (const u16*)((const u32*)ws + OFF_PK2);
    const float* pk2f = ws + OFF_PK2;
    const int* psrc = wsi + OFF_PSRC;
    float acc = 0.f, den = 0.f;
    int s = start + q;
    float w_c = 0.f, m_c = 0.f;
    bool valid = s < end;
    if (valid) {
        int p = psrc[s];
        int sn = p & 0xFFFFF, t = p >> 20;
        size_t r = (size_t)(sn * 3 + t);
        w_c = pk2f[r * 16 + 8];
        m_c = bf2f(pk2u[r * 32 + c]);
    }
    while (valid) {
        float w = w_c, m = m_c;
        int s2 = s + 4;
        bool v2 = s2 < end;
        if (v2) {
            int p = psrc[s2];
            int sn = p & 0xFFFFF, t = p >> 20;
            size_t r = (size_t)(sn * 3 + t);
            w_c = pk2f[r * 16 + 8];
            m_c = bf2f(pk2u[r * 32 + c]);
        }
        den += w;
        acc += w * m;
        s = s2; valid = v2;
    }
    acc += __shfl_xor(acc, 16);
    acc += __shfl_xor(acc, 32);
    den += __shfl_xor(den, 16);
    den += __shfl_xor(den, 32);
    float val = (end > start) ? acc / den : 0.f;
    if (q == 0) outs[wave][c] = val;
    __syncthreads();
    if (tid < 16) {
        float sum = outs[0][tid] + outs[1][tid] + outs[2][tid] + outs[3][tid];
        atomicAdd(ws + OFF_OPART + (blockIdx.x & 63) * 16 + tid, sum);
    }
}

__global__ void final_k(const float* __restrict__ res_b, float* __restrict__ ws, float* __restrict__ out) {
    int c = threadIdx.x;
    if (c < 16) {
        float s = 0.f;
        for (int r = 0; r < 64; ++r) s += ws[OFF_OPART + r * 16 + c];
        out[c] = s * (1.0f / (float)NN) + res_b[c];
    }
}

extern "C" void kernel_launch(void* const* d_in, const int* in_sizes, int n_in,
                              void* d_out, int out_size, void* d_ws, size_t ws_size,
                              hipStream_t stream) {
    const float* x     = (const float*)d_in[0];
    const int*   src   = (const int*)d_in[1];
    const int*   dst   = (const int*)d_in[2];
    // d_in[3] = ntype (unused by reference)
    const int*   etype = (const int*)d_in[4];
    const float* W1    = (const float*)d_in[5];
    const float* al1   = (const float*)d_in[6];
    const float* ar1   = (const float*)d_in[7];
    const float* W2    = (const float*)d_in[8];
    const float* al2   = (const float*)d_in[9];
    const float* ar2   = (const float*)d_in[10];
    const float* res_w = (const float*)d_in[11];
    const float* res_b = (const float*)d_in[12];
    float* ws = (float*)d_ws;
    int* wsi = (int*)d_ws;
    float* out = (float*)d_out;

    hipMemsetAsync((char*)d_ws + (size_t)OFF_BCNT * 4, 0, (size_t)1280 * 4, stream);
    hipLaunchKernelGGL(precompute, dim3(TT), dim3(512), 0, stream, W1, al1, ar1, W2, al2, ar2, ws);
    hipLaunchKernelGGL(fill_cw, dim3(56), dim3(256), 0, stream, W1, W2, res_w, ws);
    hipLaunchKernelGGL(sort_p1, dim3((EE + P1_CHUNK - 1) / P1_CHUNK), dim3(256), 0, stream, src, dst, etype, wsi);
    hipLaunchKernelGGL(sort_p2a, dim3(1), dim3(256), 0, stream, wsi);
    hipLaunchKernelGGL(sort_p2, dim3(NBUCK), dim3(256), 0, stream, wsi);
    hipLaunchKernelGGL(gemm_f, dim3((NN + 63) / 64), dim3(512), 0, stream, x, ws + OFF_CW1, ws);
    hipLaunchKernelGGL(agg1, dim3(NN / 4), dim3(256), 0, stream, wsi, ws);
    hipLaunchKernelGGL(gemm_f2, dim3((NN + 63) / 64), dim3(256), 0, stream, ws + OFF_CW2, ws);
    hipLaunchKernelGGL(agg2, dim3(NN / 4), dim3(256), 0, stream, wsi, ws);
    hipLaunchKernelGGL(final_k, dim3(1), dim3(64), 0, stream, res_b, ws, out);
}

// Round 7
// 494.001 us; speedup vs baseline: 1.0150x; 1.0150x over previous
//
#include <hip/hip_runtime.h>
#include <hip/hip_bf16.h>

typedef unsigned int u32;
typedef unsigned short u16;
typedef unsigned char u8;

#define NN 50000
#define EE 800000
#define TT 3
#define NBUCK 196        // dst>>8 buckets
#define BSTRIDE 8192     // fixed stride per bucket in TMP (max bucket ~4400)
#define P1_CHUNK 4096

// ws layout (dword offsets) — total 8,953,024 dwords = 35.8 MiB
#define OFF_C1     0         // 1536 f
#define OFF_C2     1536      // 192 f
#define OFF_BCNT   1728      // 256 i (memset-zeroed) — bucket cursors/counts
#define OFF_OPART  1984      // 1024 f (memset-zeroed)
#define OFF_BBASE  3008      // 256 i — bucket base offsets (written by sort_p2a)
#define OFF_ROWPTR 52756     // 50004 i (written by sort_p2/p2a)
#define OFF_CW1    102760    // 14336 f: folded layer-0 weights [64 k][224 c]
#define OFF_CW2    117096    // 4352 f: folded layer-1 weights [64 k][68 c]
#define OFF_PSRC   153016    // 800000 i (src | etype<<20, dst-sorted)
#define OFF_PK1    953024    // N*3 rows * 32 dw: [16 dw fp8 F][4 dw bf16 EP][12 pad]
#define OFF_TMP    953024    // overlays PK1 (dead until gemm_f): NBUCK*BSTRIDE = 1,605,632 i
#define OFF_PK2    953024    // overlays PK1 (dead after agg1): N*3 rows * 16 dw: [8 dw bf16 F2][EG f32][7 pad]
#define OFF_H      5753024   // N*64 f = 3,200,000
// memset range: dword 1728 .. 3007 (BCNT+OPART) = 1280 dwords

__device__ __forceinline__ float bf2f(u32 u) {
    union { u32 i; float f; } v; v.i = u << 16; return v.f;
}
__device__ __forceinline__ u32 f2bf(float f) {  // RNE
    union { float f; u32 i; } v; v.f = f;
    return (v.i + 0x7fffu + ((v.i >> 16) & 1u)) >> 16;
}

// C1[t][k][h] = sum_k2 W1[t][k][k2] * sum_j (al1+ar1)[t][k2][h*8+j]
// c2[t][k]   = sum_k2 W2[t][k][k2] * sum_j (al2+ar2)[t][k2][j]
__global__ void precompute(const float* __restrict__ W1, const float* __restrict__ al1,
                           const float* __restrict__ ar1, const float* __restrict__ W2,
                           const float* __restrict__ al2, const float* __restrict__ ar2,
                           float* __restrict__ ws) {
    __shared__ float a1c[64][8];
    __shared__ float a2c[16];
    int t = blockIdx.x;
    int tid = threadIdx.x;
    {
        int k2 = tid >> 3, hh = tid & 7;
        float s = 0.f;
#pragma unroll
        for (int j = 0; j < 8; ++j) {
            int idx = t * 4096 + k2 * 64 + hh * 8 + j;
            s += al1[idx] + ar1[idx];
        }
        a1c[k2][hh] = s;
    }
    if (tid < 16) {
        float s = 0.f;
#pragma unroll
        for (int j = 0; j < 16; ++j) {
            int idx = t * 256 + tid * 16 + j;
            s += al2[idx] + ar2[idx];
        }
        a2c[tid] = s;
    }
    __syncthreads();
    {
        int k = tid >> 3, hh = tid & 7;
        float s = 0.f;
#pragma unroll
        for (int k2 = 0; k2 < 64; ++k2)
            s += W1[t * 4096 + k * 64 + k2] * a1c[k2][hh];
        ws[OFF_C1 + t * 512 + k * 8 + hh] = s;
    }
    if (tid < 64) {
        float s = 0.f;
#pragma unroll
        for (int k2 = 0; k2 < 16; ++k2)
            s += W2[t * 1024 + tid * 16 + k2] * a2c[k2];
        ws[OFF_C2 + t * 64 + tid] = s;
    }
}

// Stage folded weights into global.
// CW1[k][c]: c<192 -> W1[t=c>>6][k][c&63]; 192..215 -> C1; 216..223 -> 0.
// CW2[k][c]: c<48 -> W2[t=c>>4][k][c&15]; 48..50 -> C2; 51..66 -> res_w; 67 -> 0.
__global__ __launch_bounds__(256) void fill_cw(const float* __restrict__ W1, const float* __restrict__ W2,
                        const float* __restrict__ res_w, float* __restrict__ ws) {
    int idx = blockIdx.x * 256 + threadIdx.x;
    if (idx < 14336) {
        int k = idx / 224, c = idx - k * 224;
        float v;
        if (c < 192) v = W1[(c >> 6) * 4096 + k * 64 + (c & 63)];
        else if (c < 216) v = ws[OFF_C1 + ((c - 192) >> 3) * 512 + k * 8 + ((c - 192) & 7)];
        else v = 0.f;
        ws[OFF_CW1 + idx] = v;
    }
    if (idx < 4352) {
        int k = idx / 68, c = idx - k * 68;
        float v;
        if (c < 48) v = W2[(c >> 4) * 1024 + k * 16 + (c & 15)];
        else if (c < 51) v = ws[OFF_C2 + (c - 48) * 64 + k];
        else if (c < 67) v = res_w[k * 16 + (c - 51)];
        else v = 0.f;
        ws[OFF_CW2 + idx] = v;
    }
}

// sort pass 1: bucket edges by dst>>8 into fixed-stride TMP regions.
// entry = src[15:0] | etype<<16 [17:16] | (dst&255)<<18 [25:18]
__global__ __launch_bounds__(256) void sort_p1(const int* __restrict__ src, const int* __restrict__ dst,
                        const int* __restrict__ etype, int* wsi) {
    __shared__ u32 Est[P1_CHUNK];
    __shared__ u8 Bst[P1_CHUNK];
    __shared__ int hist[NBUCK], base[NBUCK];
    int tid = threadIdx.x;
    int e0 = blockIdx.x * P1_CHUNK;
    int cnt = EE - e0; if (cnt > P1_CHUNK) cnt = P1_CHUNK;
    for (int i = tid; i < NBUCK; i += 256) hist[i] = 0;
    __syncthreads();
    for (int i = tid; i < cnt; i += 256) {
        int e = e0 + i;
        int s = src[e], d = dst[e], t = etype[e];
        int b = d >> 8;
        Est[i] = (u32)s | ((u32)t << 16) | ((u32)(d & 255) << 18);
        Bst[i] = (u8)b;
        atomicAdd(&hist[b], 1);
    }
    __syncthreads();
    for (int i = tid; i < NBUCK; i += 256) {
        int h = hist[i];
        base[i] = h ? atomicAdd(wsi + OFF_BCNT + i, h) : 0;
        hist[i] = 0;
    }
    __syncthreads();
    for (int i = tid; i < cnt; i += 256) {
        int b = Bst[i];
        int idx = base[b] + atomicAdd(&hist[b], 1);
        wsi[OFF_TMP + b * BSTRIDE + idx] = (int)Est[i];
    }
}

// sort pass 2a: exclusive scan of bucket counts -> BBASE; rowptr[NN] = EE.
__global__ __launch_bounds__(256) void sort_p2a(int* wsi) {
    __shared__ int sd[256];
    int t = threadIdx.x;
    int v = (t < NBUCK) ? wsi[OFF_BCNT + t] : 0;
    sd[t] = v;
    __syncthreads();
    for (int o = 1; o < 256; o <<= 1) {
        int u = (t >= o) ? sd[t - o] : 0;
        __syncthreads();
        sd[t] += u;
        __syncthreads();
    }
    if (t < NBUCK) wsi[OFF_BBASE + t] = sd[t] - v;  // exclusive
    if (t == 0) wsi[OFF_ROWPTR + NN] = EE;
}

// sort pass 2: per bucket, count per-dst in LDS, scan -> rowptr, scatter into
// final psrc window (16 KB, L2-resident). psrc format: src | etype<<20.
__global__ __launch_bounds__(256) void sort_p2(int* wsi) {
    __shared__ int cnt[256], sd[256], lrpx[256];
    int b = blockIdx.x;
    int tid = threadIdx.x;
    int nb = wsi[OFF_BCNT + b];
    int gbase = wsi[OFF_BBASE + b];
    cnt[tid] = 0;
    __syncthreads();
    const int* tmp = wsi + OFF_TMP + b * BSTRIDE;
    for (int i = tid; i < nb; i += 256) {
        int e = tmp[i];
        atomicAdd(&cnt[(e >> 18) & 255], 1);
    }
    __syncthreads();
    int v = cnt[tid];
    sd[tid] = v;
    __syncthreads();
    for (int o = 1; o < 256; o <<= 1) {
        int u = (tid >= o) ? sd[tid - o] : 0;
        __syncthreads();
        sd[tid] += u;
        __syncthreads();
    }
    int ex = sd[tid] - v;  // exclusive prefix within bucket
    lrpx[tid] = ex;
    int d = b * 256 + tid;
    if (d < NN) wsi[OFF_ROWPTR + d] = gbase + ex;
    cnt[tid] = 0;
    __syncthreads();
    for (int i = tid; i < nb; i += 256) {
        int e = tmp[i];
        int dres = (e >> 18) & 255;
        int slot = gbase + lrpx[dres] + atomicAdd(&cnt[dres], 1);
        wsi[OFF_PSRC + slot] = (e & 0xFFFF) | (((e >> 16) & 3) << 20);
    }
}

// PK1[n][t] row (32 dw): F fp8 (dw 0-15) + EP bf16 (dw 16-19).
// 8 waves; wave = 28-col slice (weights wave-uniform -> SGPRs via s_load),
// lane = node. K split in two halves reusing a 32-reg x buffer so the whole
// kernel fits the allocator's ~80-VGPR cap (r4/r5/r6 lesson: cap can't be
// raised; xr[64] spilled ~21 dw/thread -> 48 MB phantom WRITE_SIZE).
__global__ __launch_bounds__(512)
void gemm_f(const float* __restrict__ x, const float* __restrict__ cw,
            float* __restrict__ ws) {
    int tid = threadIdx.x;
    int wave = __builtin_amdgcn_readfirstlane(tid >> 6);
    int lane = tid & 63;
    int n0 = blockIdx.x * 64;
    int n = n0 + lane;
    bool act = n < NN;
    const float4* xg = (const float4*)(x + (size_t)n * 64);
    int cbase = wave * 28;
    float acc[28];
#pragma unroll
    for (int i = 0; i < 28; ++i) acc[i] = 0.f;
    float wA[28], wB[28];
#pragma unroll
    for (int j = 0; j < 28; ++j) wA[j] = cw[cbase + j];
    float xr[32];
#pragma unroll
    for (int h = 0; h < 2; ++h) {
#pragma unroll
        for (int i = 0; i < 8; ++i)
            *(float4*)(xr + 4 * i) = act ? xg[h * 8 + i] : make_float4(0.f, 0.f, 0.f, 0.f);
#pragma unroll
        for (int kk = 0; kk < 32; kk += 2) {
            int k = h * 32 + kk;
#pragma unroll
            for (int j = 0; j < 28; ++j) wB[j] = cw[(k + 1) * 224 + cbase + j];
            float xv = xr[kk];
#pragma unroll
            for (int j = 0; j < 28; ++j) acc[j] = fmaf(xv, wA[j], acc[j]);
            if (k + 2 < 64) {
#pragma unroll
                for (int j = 0; j < 28; ++j) wA[j] = cw[(k + 2) * 224 + cbase + j];
            }
            float xv2 = xr[kk + 1];
#pragma unroll
            for (int j = 0; j < 28; ++j) acc[j] = fmaf(xv2, wB[j], acc[j]);
        }
    }
    if (act) {
        u32* row = (u32*)ws + OFF_PK1 + (size_t)n * 96;
#pragma unroll
        for (int g = 0; g < 7; ++g) {
            int col = cbase + 4 * g;
            float v0 = acc[4*g], v1 = acc[4*g+1], v2 = acc[4*g+2], v3 = acc[4*g+3];
            if (col < 192) {
                int t = col >> 6, ci = col & 63;
                int dw = __builtin_amdgcn_cvt_pk_fp8_f32(v0, v1, 0, false);
                dw = __builtin_amdgcn_cvt_pk_fp8_f32(v2, v3, dw, true);
                row[t * 32 + (ci >> 2)] = (u32)dw;
            } else if (col < 216) {
                int jj = col - 192;
                int t = jj >> 3, rem = jj & 7;  // rem in {0,4}
                v0 = v0 > 0.f ? v0 : 0.2f * v0;
                v1 = v1 > 0.f ? v1 : 0.2f * v1;
                v2 = v2 > 0.f ? v2 : 0.2f * v2;
                v3 = v3 > 0.f ? v3 : 0.2f * v3;
                row[t * 32 + 16 + (rem >> 1)]     = f2bf(__expf(v0)) | (f2bf(__expf(v1)) << 16);
                row[t * 32 + 16 + (rem >> 1) + 1] = f2bf(__expf(v2)) | (f2bf(__expf(v3)) << 16);
            }
        }
    }
}

// layer0 fused softmax+aggregate — 4-way edge-parallel per wave.
__global__ __launch_bounds__(256) void agg1(const int* __restrict__ wsi, float* __restrict__ ws) {
    int tid = threadIdx.x;
    int wave = tid >> 6, lane = tid & 63;
    int q = lane >> 4;
    int cg = lane & 15;
    int d = blockIdx.x * 4 + wave;
    int epw = cg >> 2;
    int sh_ep = ((cg >> 1) & 1) * 16;
    int start = wsi[OFF_ROWPTR + d], end = wsi[OFF_ROWPTR + d + 1];
    const u32* pk = (const u32*)ws + OFF_PK1;
    const int* psrc = wsi + OFF_PSRC;
    float acc0 = 0.f, acc1 = 0.f, acc2 = 0.f, acc3 = 0.f, den = 0.f;
    int s = start + q;
    u32 fdw_c = 0, epdw_c = 0;
    int p1 = 0;
    bool valid = s < end;
    if (valid) {
        int p = psrc[s];
        int sn = p & 0xFFFFF, t = p >> 20;
        size_t base = (size_t)(sn * 3 + t) * 32;
        fdw_c = pk[base + cg];
        epdw_c = pk[base + 16 + epw];
    }
    if (s + 4 < end) p1 = psrc[s + 4];
    while (valid) {
        u32 fdw = fdw_c, epdw = epdw_c;
        bool v1 = s + 4 < end;
        if (v1) {
            int sn = p1 & 0xFFFFF, t = p1 >> 20;
            size_t base = (size_t)(sn * 3 + t) * 32;
            fdw_c = pk[base + cg];
            epdw_c = pk[base + 16 + epw];
        }
        if (s + 8 < end) p1 = psrc[s + 8];
        float w = bf2f((epdw >> sh_ep) & 0xffffu);
        float m0 = __builtin_amdgcn_cvt_f32_fp8((int)fdw, 0);
        float m1 = __builtin_amdgcn_cvt_f32_fp8((int)(fdw >> 8), 0);
        float m2 = __builtin_amdgcn_cvt_f32_fp8((int)(fdw >> 16), 0);
        float m3 = __builtin_amdgcn_cvt_f32_fp8((int)(fdw >> 24), 0);
        den += w;
        acc0 += w * m0;
        acc1 += w * m1;
        acc2 += w * m2;
        acc3 += w * m3;
        s += 4;
        valid = v1;
    }
    acc0 += __shfl_xor(acc0, 16); acc0 += __shfl_xor(acc0, 32);
    acc1 += __shfl_xor(acc1, 16); acc1 += __shfl_xor(acc1, 32);
    acc2 += __shfl_xor(acc2, 16); acc2 += __shfl_xor(acc2, 32);
    acc3 += __shfl_xor(acc3, 16); acc3 += __shfl_xor(acc3, 32);
    den  += __shfl_xor(den, 16);  den  += __shfl_xor(den, 32);
    if (q == 0) {
        float dn = (end > start) ? den : 1.f;
        float v0 = acc0 / dn, v1 = acc1 / dn, v2 = acc2 / dn, v3 = acc3 / dn;
        v0 = v0 > 0.f ? v0 : __expf(v0) - 1.f;  // ELU
        v1 = v1 > 0.f ? v1 : __expf(v1) - 1.f;
        v2 = v2 > 0.f ? v2 : __expf(v2) - 1.f;
        v3 = v3 > 0.f ? v3 : __expf(v3) - 1.f;
        *(float4*)(ws + OFF_H + (size_t)d * 64 + cg * 4) = make_float4(v0, v1, v2, v3);
    }
}

// PK2[n][t] = [16 bf16 F2][EG f32]; residual partials to OPART.
// 4 waves; wave = 17-col slice, lane = node; H row in two 32-reg halves.
__global__ __launch_bounds__(256)
void gemm_f2(const float* __restrict__ cw, float* __restrict__ ws) {
    __shared__ float Rs[64][17];
    int tid = threadIdx.x;
    int wave = __builtin_amdgcn_readfirstlane(tid >> 6);
    int lane = tid & 63;
    int n0 = blockIdx.x * 64;
    int n = n0 + lane;
    bool act = n < NN;
    const float4* hg = (const float4*)(ws + OFF_H + (size_t)n * 64);
    int cbase = wave * 17;
    float acc[17];
#pragma unroll
    for (int i = 0; i < 17; ++i) acc[i] = 0.f;
    float wA[17], wB[17];
#pragma unroll
    for (int j = 0; j < 17; ++j) wA[j] = cw[cbase + j];
    float hr[32];
#pragma unroll
    for (int h = 0; h < 2; ++h) {
#pragma unroll
        for (int i = 0; i < 8; ++i)
            *(float4*)(hr + 4 * i) = act ? hg[h * 8 + i] : make_float4(0.f, 0.f, 0.f, 0.f);
#pragma unroll
        for (int kk = 0; kk < 32; kk += 2) {
            int k = h * 32 + kk;
#pragma unroll
            for (int j = 0; j < 17; ++j) wB[j] = cw[(k + 1) * 68 + cbase + j];
            float hv = hr[kk];
#pragma unroll
            for (int j = 0; j < 17; ++j) acc[j] = fmaf(hv, wA[j], acc[j]);
            if (k + 2 < 64) {
#pragma unroll
                for (int j = 0; j < 17; ++j) wA[j] = cw[(k + 2) * 68 + cbase + j];
            }
            float hv2 = hr[kk + 1];
#pragma unroll
            for (int j = 0; j < 17; ++j) acc[j] = fmaf(hv2, wB[j], acc[j]);
        }
    }
    u16* pk2u = (u16*)((u32*)ws + OFF_PK2);
#pragma unroll
    for (int i = 0; i < 17; ++i) {
        int col = cbase + i;
        if (col < 48) {
            if (act) {
                int t = col >> 4, c2 = col & 15;
                pk2u[((size_t)n * 3 + t) * 32 + c2] = (u16)f2bf(acc[i]);
            }
        } else if (col < 51) {
            if (act) {
                float v = acc[i]; v = v > 0.f ? v : 0.2f * v;
                ws[OFF_PK2 + ((size_t)n * 3 + (col - 48)) * 16 + 8] = __expf(v);
            }
        } else if (col < 67) {
            Rs[lane][col - 51] = acc[i];
        }
    }
    __syncthreads();
    if (tid < 16) {
        float s = 0.f;
#pragma unroll 8
        for (int r = 0; r < 64; ++r) s += Rs[r][tid];
        atomicAdd(ws + OFF_OPART + (blockIdx.x & 63) * 16 + tid, s);
    }
}

// layer1 fused — PK2 single-line gathers.
__global__ __launch_bounds__(256) void agg2(const int* __restrict__ wsi, float* __restrict__ ws) {
    __shared__ float outs[4][16];
    int tid = threadIdx.x;
    int wave = tid >> 6, lane = tid & 63;
    int q = lane >> 4, c = lane & 15;
    int d = blockIdx.x * 4 + wave;
    int start = wsi[OFF_ROWPTR + d], end = wsi[OFF_ROWPTR + d + 1];
    const u16* pk2u = (const u16*)((const u32*)ws + OFF_PK2);
    const float* pk2f = ws + OFF_PK2;
    const int* psrc = wsi + OFF_PSRC;
    float acc = 0.f, den = 0.f;
    int s = start + q;
    float w_c = 0.f, m_c = 0.f;
    bool valid = s < end;
    if (valid) {
        int p = psrc[s];
        int sn = p & 0xFFFFF, t = p >> 20;
        size_t r = (size_t)(sn * 3 + t);
        w_c = pk2f[r * 16 + 8];
        m_c = bf2f(pk2u[r * 32 + c]);
    }
    while (valid) {
        float w = w_c, m = m_c;
        int s2 = s + 4;
        bool v2 = s2 < end;
        if (v2) {
            int p = psrc[s2];
            int sn = p & 0xFFFFF, t = p >> 20;
            size_t r = (size_t)(sn * 3 + t);
            w_c = pk2f[r * 16 + 8];
            m_c = bf2f(pk2u[r * 32 + c]);
        }
        den += w;
        acc += w * m;
        s = s2; valid = v2;
    }
    acc += __shfl_xor(acc, 16);
    acc += __shfl_xor(acc, 32);
    den += __shfl_xor(den, 16);
    den += __shfl_xor(den, 32);
    float val = (end > start) ? acc / den : 0.f;
    if (q == 0) outs[wave][c] = val;
    __syncthreads();
    if (tid < 16) {
        float sum = outs[0][tid] + outs[1][tid] + outs[2][tid] + outs[3][tid];
        atomicAdd(ws + OFF_OPART + (blockIdx.x & 63) * 16 + tid, sum);
    }
}

__global__ void final_k(const float* __restrict__ res_b, float* __restrict__ ws, float* __restrict__ out) {
    int c = threadIdx.x;
    if (c < 16) {
        float s = 0.f;
        for (int r = 0; r < 64; ++r) s += ws[OFF_OPART + r * 16 + c];
        out[c] = s * (1.0f / (float)NN) + res_b[c];
    }
}

extern "C" void kernel_launch(void* const* d_in, const int* in_sizes, int n_in,
                              void* d_out, int out_size, void* d_ws, size_t ws_size,
                              hipStream_t stream) {
    const float* x     = (const float*)d_in[0];
    const int*   src   = (const int*)d_in[1];
    const int*   dst   = (const int*)d_in[2];
    // d_in[3] = ntype (unused by reference)
    const int*   etype = (const int*)d_in[4];
    const float* W1    = (const float*)d_in[5];
    const float* al1   = (const float*)d_in[6];
    const float* ar1   = (const float*)d_in[7];
    const float* W2    = (const float*)d_in[8];
    const float* al2   = (const float*)d_in[9];
    const float* ar2   = (const float*)d_in[10];
    const float* res_w = (const float*)d_in[11];
    const float* res_b = (const float*)d_in[12];
    float* ws = (float*)d_ws;
    int* wsi = (int*)d_ws;
    float* out = (float*)d_out;

    hipMemsetAsync((char*)d_ws + (size_t)OFF_BCNT * 4, 0, (size_t)1280 * 4, stream);
    hipLaunchKernelGGL(precompute, dim3(TT), dim3(512), 0, stream, W1, al1, ar1, W2, al2, ar2, ws);
    hipLaunchKernelGGL(fill_cw, dim3(56), dim3(256), 0, stream, W1, W2, res_w, ws);
    hipLaunchKernelGGL(sort_p1, dim3((EE + P1_CHUNK - 1) / P1_CHUNK), dim3(256), 0, stream, src, dst, etype, wsi);
    hipLaunchKernelGGL(sort_p2a, dim3(1), dim3(256), 0, stream, wsi);
    hipLaunchKernelGGL(sort_p2, dim3(NBUCK), dim3(256), 0, stream, wsi);
    hipLaunchKernelGGL(gemm_f, dim3((NN + 63) / 64), dim3(512), 0, stream, x, ws + OFF_CW1, ws);
    hipLaunchKernelGGL(agg1, dim3(NN / 4), dim3(256), 0, stream, wsi, ws);
    hipLaunchKernelGGL(gemm_f2, dim3((NN + 63) / 64), dim3(256), 0, stream, ws + OFF_CW2, ws);
    hipLaunchKernelGGL(agg2, dim3(NN / 4), dim3(256), 0, stream, wsi, ws);
    hipLaunchKernelGGL(final_k, dim3(1), dim3(64), 0, stream, res_b, ws, out);
}

// Round 8
// 253.852 us; speedup vs baseline: 1.9752x; 1.9460x over previous
//
#include <hip/hip_runtime.h>
#include <hip/hip_bf16.h>

typedef unsigned int u32;
typedef unsigned short u16;
typedef unsigned char u8;

#define NN 50000
#define EE 800000
#define TT 3
#define NBUCK 196        // dst>>8 buckets
#define BSTRIDE 8192     // fixed stride per bucket in TMP (max bucket ~4400)
#define P1_CHUNK 4096

// ws layout (dword offsets) — total 8,953,024 dwords = 35.8 MiB
#define OFF_C1     0         // 1536 f
#define OFF_C2     1536      // 192 f
#define OFF_BCNT   1728      // 256 i (memset-zeroed) — bucket cursors/counts
#define OFF_OPART  1984      // 1024 f (memset-zeroed)
#define OFF_BBASE  3008      // 256 i — bucket base offsets (written by sort_p2a)
#define OFF_ROWPTR 52756     // 50004 i (written by sort_p2/p2a)
#define OFF_CW1    102760    // 14336 f: folded layer-0 weights [64 k][224 c]
#define OFF_CW2    117096    // 4352 f: folded layer-1 weights [64 k][68 c]
#define OFF_PSRC   153016    // 800000 i (src | etype<<20, dst-sorted)
#define OFF_PK1    953024    // N*3 rows * 32 dw: [16 dw fp8 F][4 dw bf16 EP][12 pad]
#define OFF_TMP    953024    // overlays PK1 (dead until gemm_f): NBUCK*BSTRIDE = 1,605,632 i
#define OFF_PK2    953024    // overlays PK1 (dead after agg1): N*3 rows * 16 dw: [8 dw bf16 F2][EG f32][7 pad]
#define OFF_H      5753024   // N*64 f = 3,200,000
// memset range: dword 1728 .. 3007 (BCNT+OPART) = 1280 dwords

__device__ __forceinline__ float bf2f(u32 u) {
    union { u32 i; float f; } v; v.i = u << 16; return v.f;
}
__device__ __forceinline__ u32 f2bf(float f) {  // RNE
    union { float f; u32 i; } v; v.f = f;
    return (v.i + 0x7fffu + ((v.i >> 16) & 1u)) >> 16;
}

// C1[t][k][h] = sum_k2 W1[t][k][k2] * sum_j (al1+ar1)[t][k2][h*8+j]
// c2[t][k]   = sum_k2 W2[t][k][k2] * sum_j (al2+ar2)[t][k2][j]
__global__ void precompute(const float* __restrict__ W1, const float* __restrict__ al1,
                           const float* __restrict__ ar1, const float* __restrict__ W2,
                           const float* __restrict__ al2, const float* __restrict__ ar2,
                           float* __restrict__ ws) {
    __shared__ float a1c[64][8];
    __shared__ float a2c[16];
    int t = blockIdx.x;
    int tid = threadIdx.x;
    {
        int k2 = tid >> 3, hh = tid & 7;
        float s = 0.f;
#pragma unroll
        for (int j = 0; j < 8; ++j) {
            int idx = t * 4096 + k2 * 64 + hh * 8 + j;
            s += al1[idx] + ar1[idx];
        }
        a1c[k2][hh] = s;
    }
    if (tid < 16) {
        float s = 0.f;
#pragma unroll
        for (int j = 0; j < 16; ++j) {
            int idx = t * 256 + tid * 16 + j;
            s += al2[idx] + ar2[idx];
        }
        a2c[tid] = s;
    }
    __syncthreads();
    {
        int k = tid >> 3, hh = tid & 7;
        float s = 0.f;
#pragma unroll
        for (int k2 = 0; k2 < 64; ++k2)
            s += W1[t * 4096 + k * 64 + k2] * a1c[k2][hh];
        ws[OFF_C1 + t * 512 + k * 8 + hh] = s;
    }
    if (tid < 64) {
        float s = 0.f;
#pragma unroll
        for (int k2 = 0; k2 < 16; ++k2)
            s += W2[t * 1024 + tid * 16 + k2] * a2c[k2];
        ws[OFF_C2 + t * 64 + tid] = s;
    }
}

// Stage folded weights into global.
// CW1[k][c]: c<192 -> W1[t=c>>6][k][c&63]; 192..215 -> C1; 216..223 -> 0.
// CW2[k][c]: c<48 -> W2[t=c>>4][k][c&15]; 48..50 -> C2; 51..66 -> res_w; 67 -> 0.
__global__ __launch_bounds__(256) void fill_cw(const float* __restrict__ W1, const float* __restrict__ W2,
                        const float* __restrict__ res_w, float* __restrict__ ws) {
    int idx = blockIdx.x * 256 + threadIdx.x;
    if (idx < 14336) {
        int k = idx / 224, c = idx - k * 224;
        float v;
        if (c < 192) v = W1[(c >> 6) * 4096 + k * 64 + (c & 63)];
        else if (c < 216) v = ws[OFF_C1 + ((c - 192) >> 3) * 512 + k * 8 + ((c - 192) & 7)];
        else v = 0.f;
        ws[OFF_CW1 + idx] = v;
    }
    if (idx < 4352) {
        int k = idx / 68, c = idx - k * 68;
        float v;
        if (c < 48) v = W2[(c >> 4) * 1024 + k * 16 + (c & 15)];
        else if (c < 51) v = ws[OFF_C2 + (c - 48) * 64 + k];
        else if (c < 67) v = res_w[k * 16 + (c - 51)];
        else v = 0.f;
        ws[OFF_CW2 + idx] = v;
    }
}

// sort pass 1: bucket edges by dst>>8 into fixed-stride TMP regions.
// entry = src[15:0] | etype<<16 [17:16] | (dst&255)<<18 [25:18]
__global__ __launch_bounds__(256) void sort_p1(const int* __restrict__ src, const int* __restrict__ dst,
                        const int* __restrict__ etype, int* wsi) {
    __shared__ u32 Est[P1_CHUNK];
    __shared__ u8 Bst[P1_CHUNK];
    __shared__ int hist[NBUCK], base[NBUCK];
    int tid = threadIdx.x;
    int e0 = blockIdx.x * P1_CHUNK;
    int cnt = EE - e0; if (cnt > P1_CHUNK) cnt = P1_CHUNK;
    for (int i = tid; i < NBUCK; i += 256) hist[i] = 0;
    __syncthreads();
    for (int i = tid; i < cnt; i += 256) {
        int e = e0 + i;
        int s = src[e], d = dst[e], t = etype[e];
        int b = d >> 8;
        Est[i] = (u32)s | ((u32)t << 16) | ((u32)(d & 255) << 18);
        Bst[i] = (u8)b;
        atomicAdd(&hist[b], 1);
    }
    __syncthreads();
    for (int i = tid; i < NBUCK; i += 256) {
        int h = hist[i];
        base[i] = h ? atomicAdd(wsi + OFF_BCNT + i, h) : 0;
        hist[i] = 0;
    }
    __syncthreads();
    for (int i = tid; i < cnt; i += 256) {
        int b = Bst[i];
        int idx = base[b] + atomicAdd(&hist[b], 1);
        wsi[OFF_TMP + b * BSTRIDE + idx] = (int)Est[i];
    }
}

// sort pass 2a: exclusive scan of bucket counts -> BBASE; rowptr[NN] = EE.
__global__ __launch_bounds__(256) void sort_p2a(int* wsi) {
    __shared__ int sd[256];
    int t = threadIdx.x;
    int v = (t < NBUCK) ? wsi[OFF_BCNT + t] : 0;
    sd[t] = v;
    __syncthreads();
    for (int o = 1; o < 256; o <<= 1) {
        int u = (t >= o) ? sd[t - o] : 0;
        __syncthreads();
        sd[t] += u;
        __syncthreads();
    }
    if (t < NBUCK) wsi[OFF_BBASE + t] = sd[t] - v;  // exclusive
    if (t == 0) wsi[OFF_ROWPTR + NN] = EE;
}

// sort pass 2: per bucket, count per-dst in LDS, scan -> rowptr, scatter into
// final psrc window (16 KB, L2-resident). psrc format: src | etype<<20.
__global__ __launch_bounds__(256) void sort_p2(int* wsi) {
    __shared__ int cnt[256], sd[256], lrpx[256];
    int b = blockIdx.x;
    int tid = threadIdx.x;
    int nb = wsi[OFF_BCNT + b];
    int gbase = wsi[OFF_BBASE + b];
    cnt[tid] = 0;
    __syncthreads();
    const int* tmp = wsi + OFF_TMP + b * BSTRIDE;
    for (int i = tid; i < nb; i += 256) {
        int e = tmp[i];
        atomicAdd(&cnt[(e >> 18) & 255], 1);
    }
    __syncthreads();
    int v = cnt[tid];
    sd[tid] = v;
    __syncthreads();
    for (int o = 1; o < 256; o <<= 1) {
        int u = (tid >= o) ? sd[tid - o] : 0;
        __syncthreads();
        sd[tid] += u;
        __syncthreads();
    }
    int ex = sd[tid] - v;  // exclusive prefix within bucket
    lrpx[tid] = ex;
    int d = b * 256 + tid;
    if (d < NN) wsi[OFF_ROWPTR + d] = gbase + ex;
    cnt[tid] = 0;
    __syncthreads();
    for (int i = tid; i < nb; i += 256) {
        int e = tmp[i];
        int dres = (e >> 18) & 255;
        int slot = gbase + lrpx[dres] + atomicAdd(&cnt[dres], 1);
        wsi[OFF_PSRC + slot] = (e & 0xFFFF) | (((e >> 16) & 3) << 20);
    }
}

// PK1[n][t] row (32 dw): F fp8 (dw 0-15) + EP bf16 (dw 16-19).
// r3-exact (51 µs proven): 8 waves; wave = 28-col slice, lane = node,
// Xs LDS staging, weights from global cw (wave-uniform). r4-r7 lesson:
// register-resident x variants all regress (phantom traffic) — keep this.
__global__ __launch_bounds__(512) void gemm_f(const float* __restrict__ x, const float* __restrict__ cw,
                       float* __restrict__ ws) {
    __shared__ alignas(16) float Xs[64 * 65];
    int tid = threadIdx.x;
    int wave = __builtin_amdgcn_readfirstlane(tid >> 6);
    int lane = tid & 63;
    int n0 = blockIdx.x * 64;
    {
        const float4* xg = (const float4*)(x + (size_t)n0 * 64);
        for (int q = tid; q < 1024; q += 512) {
            int row = q >> 4;
            float4 v = (n0 + row < NN) ? xg[q] : make_float4(0.f, 0.f, 0.f, 0.f);
            *(float4*)(Xs + row * 65 + (q & 15) * 4) = v;
        }
    }
    __syncthreads();
    int cbase = wave * 28;
    float acc[28];
#pragma unroll
    for (int i = 0; i < 28; ++i) acc[i] = 0.f;
    const float* xrow = Xs + lane * 65;
    float wA[28], wB[28];
#pragma unroll
    for (int j = 0; j < 28; ++j) wA[j] = cw[cbase + j];
    for (int k = 0; k < 64; k += 2) {
#pragma unroll
        for (int j = 0; j < 28; ++j) wB[j] = cw[(k + 1) * 224 + cbase + j];
        float xv = xrow[k];
#pragma unroll
        for (int j = 0; j < 28; ++j) acc[j] = fmaf(xv, wA[j], acc[j]);
        if (k + 2 < 64) {
#pragma unroll
            for (int j = 0; j < 28; ++j) wA[j] = cw[(k + 2) * 224 + cbase + j];
        }
        float xv2 = xrow[k + 1];
#pragma unroll
        for (int j = 0; j < 28; ++j) acc[j] = fmaf(xv2, wB[j], acc[j]);
    }
    int n = n0 + lane;
    if (n < NN) {
        u32* row = (u32*)ws + OFF_PK1 + (size_t)n * 96;
#pragma unroll
        for (int g = 0; g < 7; ++g) {
            int col = cbase + 4 * g;
            float v0 = acc[4*g], v1 = acc[4*g+1], v2 = acc[4*g+2], v3 = acc[4*g+3];
            if (col < 192) {
                int t = col >> 6, ci = col & 63;
                int dw = __builtin_amdgcn_cvt_pk_fp8_f32(v0, v1, 0, false);
                dw = __builtin_amdgcn_cvt_pk_fp8_f32(v2, v3, dw, true);
                row[t * 32 + (ci >> 2)] = (u32)dw;
            } else if (col < 216) {
                int jj = col - 192;
                int t = jj >> 3, rem = jj & 7;  // rem in {0,4}
                v0 = v0 > 0.f ? v0 : 0.2f * v0;
                v1 = v1 > 0.f ? v1 : 0.2f * v1;
                v2 = v2 > 0.f ? v2 : 0.2f * v2;
                v3 = v3 > 0.f ? v3 : 0.2f * v3;
                row[t * 32 + 16 + (rem >> 1)]     = f2bf(__expf(v0)) | (f2bf(__expf(v1)) << 16);
                row[t * 32 + 16 + (rem >> 1) + 1] = f2bf(__expf(v2)) | (f2bf(__expf(v3)) << 16);
            }
        }
    }
}

// layer0 fused softmax+aggregate — 8-way edge-parallel per wave.
// Lane layout: q = lane>>3 (edge slot, stride 8), cg = lane&7 (channels
// 8cg..8cg+7 = head cg: one aligned uint2 F-load + one EP word per edge).
// 2-deep psrc pipeline as before.
__global__ __launch_bounds__(256) void agg1(const int* __restrict__ wsi, float* __restrict__ ws) {
    int tid = threadIdx.x;
    int wave = tid >> 6, lane = tid & 63;
    int q = lane >> 3;
    int cg = lane & 7;
    int d = blockIdx.x * 4 + wave;
    int epw = cg >> 1;
    int sh_ep = (cg & 1) * 16;
    int start = wsi[OFF_ROWPTR + d], end = wsi[OFF_ROWPTR + d + 1];
    const u32* pk = (const u32*)ws + OFF_PK1;
    const int* psrc = wsi + OFF_PSRC;
    float acc[8];
#pragma unroll
    for (int i = 0; i < 8; ++i) acc[i] = 0.f;
    float den = 0.f;
    int s = start + q;
    u32 f0_c = 0, f1_c = 0, ep_c = 0;
    int p1 = 0;
    bool valid = s < end;
    if (valid) {
        int p = psrc[s];
        int sn = p & 0xFFFFF, t = p >> 20;
        size_t base = (size_t)(sn * 3 + t) * 32;
        uint2 f = *(const uint2*)(pk + base + 2 * cg);
        f0_c = f.x; f1_c = f.y;
        ep_c = pk[base + 16 + epw];
    }
    if (s + 8 < end) p1 = psrc[s + 8];
    while (valid) {
        u32 f0 = f0_c, f1 = f1_c, ep = ep_c;
        bool v1 = s + 8 < end;
        if (v1) {
            int sn = p1 & 0xFFFFF, t = p1 >> 20;
            size_t base = (size_t)(sn * 3 + t) * 32;
            uint2 f = *(const uint2*)(pk + base + 2 * cg);
            f0_c = f.x; f1_c = f.y;
            ep_c = pk[base + 16 + epw];
        }
        if (s + 16 < end) p1 = psrc[s + 16];
        float w = bf2f((ep >> sh_ep) & 0xffffu);
        den += w;
        acc[0] += w * __builtin_amdgcn_cvt_f32_fp8((int)f0, 0);
        acc[1] += w * __builtin_amdgcn_cvt_f32_fp8((int)(f0 >> 8), 0);
        acc[2] += w * __builtin_amdgcn_cvt_f32_fp8((int)(f0 >> 16), 0);
        acc[3] += w * __builtin_amdgcn_cvt_f32_fp8((int)(f0 >> 24), 0);
        acc[4] += w * __builtin_amdgcn_cvt_f32_fp8((int)f1, 0);
        acc[5] += w * __builtin_amdgcn_cvt_f32_fp8((int)(f1 >> 8), 0);
        acc[6] += w * __builtin_amdgcn_cvt_f32_fp8((int)(f1 >> 16), 0);
        acc[7] += w * __builtin_amdgcn_cvt_f32_fp8((int)(f1 >> 24), 0);
        s += 8;
        valid = v1;
    }
    // reduce over the 8 edge slots (lane bits 3,4,5)
#pragma unroll
    for (int i = 0; i < 8; ++i) {
        acc[i] += __shfl_xor(acc[i], 8);
        acc[i] += __shfl_xor(acc[i], 16);
        acc[i] += __shfl_xor(acc[i], 32);
    }
    den += __shfl_xor(den, 8);
    den += __shfl_xor(den, 16);
    den += __shfl_xor(den, 32);
    if (q == 0) {
        float dn = (end > start) ? den : 1.f;
        float o[8];
#pragma unroll
        for (int i = 0; i < 8; ++i) {
            float v = acc[i] / dn;
            o[i] = v > 0.f ? v : __expf(v) - 1.f;  // ELU
        }
        float* dst = ws + OFF_H + (size_t)d * 64 + cg * 8;
        *(float4*)dst       = make_float4(o[0], o[1], o[2], o[3]);
        *(float4*)(dst + 4) = make_float4(o[4], o[5], o[6], o[7]);
    }
}

// PK2[n][t] = [16 bf16 F2][EG f32]; residual partials to OPART.
// r3-exact: 4 waves; wave = 17-col slice, lane = node, Hs LDS staging.
__global__ __launch_bounds__(256) void gemm_f2(const float* __restrict__ cw, float* __restrict__ ws) {
    __shared__ alignas(16) float Hs[64 * 65];
    __shared__ float Rs[64][17];
    int tid = threadIdx.x;
    int wave = __builtin_amdgcn_readfirstlane(tid >> 6);
    int lane = tid & 63;
    int n0 = blockIdx.x * 64;
    {
        const float4* hg = (const float4*)(ws + OFF_H + (size_t)n0 * 64);
        for (int q = tid; q < 1024; q += 256) {
            int row = q >> 4;
            float4 v = (n0 + row < NN) ? hg[q] : make_float4(0.f, 0.f, 0.f, 0.f);
            *(float4*)(Hs + row * 65 + (q & 15) * 4) = v;
        }
    }
    __syncthreads();
    int cbase = wave * 17;
    float acc[17];
#pragma unroll
    for (int i = 0; i < 17; ++i) acc[i] = 0.f;
    const float* hrow = Hs + lane * 65;
    float wA[17], wB[17];
#pragma unroll
    for (int j = 0; j < 17; ++j) wA[j] = cw[cbase + j];
    for (int k = 0; k < 64; k += 2) {
#pragma unroll
        for (int j = 0; j < 17; ++j) wB[j] = cw[(k + 1) * 68 + cbase + j];
        float hv = hrow[k];
#pragma unroll
        for (int j = 0; j < 17; ++j) acc[j] = fmaf(hv, wA[j], acc[j]);
        if (k + 2 < 64) {
#pragma unroll
            for (int j = 0; j < 17; ++j) wA[j] = cw[(k + 2) * 68 + cbase + j];
        }
        float hv2 = hrow[k + 1];
#pragma unroll
        for (int j = 0; j < 17; ++j) acc[j] = fmaf(hv2, wB[j], acc[j]);
    }
    int n = n0 + lane;
    u16* pk2u = (u16*)((u32*)ws + OFF_PK2);
#pragma unroll
    for (int i = 0; i < 17; ++i) {
        int col = cbase + i;
        if (col < 48) {
            if (n < NN) {
                int t = col >> 4, c2 = col & 15;
                pk2u[((size_t)n * 3 + t) * 32 + c2] = (u16)f2bf(acc[i]);
            }
        } else if (col < 51) {
            if (n < NN) {
                float v = acc[i]; v = v > 0.f ? v : 0.2f * v;
                ws[OFF_PK2 + ((size_t)n * 3 + (col - 48)) * 16 + 8] = __expf(v);
            }
        } else if (col < 67) {
            Rs[lane][col - 51] = acc[i];
        }
    }
    __syncthreads();
    if (tid < 16) {
        float s = 0.f;
#pragma unroll 8
        for (int r = 0; r < 64; ++r) s += Rs[r][tid];
        atomicAdd(ws + OFF_OPART + (blockIdx.x & 63) * 16 + tid, s);
    }
}

// layer1 fused — PK2 single-line gathers.
__global__ __launch_bounds__(256) void agg2(const int* __restrict__ wsi, float* __restrict__ ws) {
    __shared__ float outs[4][16];
    int tid = threadIdx.x;
    int wave = tid >> 6, lane = tid & 63;
    int q = lane >> 4, c = lane & 15;
    int d = blockIdx.x * 4 + wave;
    int start = wsi[OFF_ROWPTR + d], end = wsi[OFF_ROWPTR + d + 1];
    const u16* pk2u = (const u16*)((const u32*)ws + OFF_PK2);
    const float* pk2f = ws + OFF_PK2;
    const int* psrc = wsi + OFF_PSRC;
    float acc = 0.f, den = 0.f;
    int s = start + q;
    float w_c = 0.f, m_c = 0.f;
    bool valid = s < end;
    if (valid) {
        int p = psrc[s];
        int sn = p & 0xFFFFF, t = p >> 20;
        size_t r = (size_t)(sn * 3 + t);
        w_c = pk2f[r * 16 + 8];
        m_c = bf2f(pk2u[r * 32 + c]);
    }
    while (valid) {
        float w = w_c, m = m_c;
        int s2 = s + 4;
        bool v2 = s2 < end;
        if (v2) {
            int p = psrc[s2];
            int sn = p & 0xFFFFF, t = p >> 20;
            size_t r = (size_t)(sn * 3 + t);
            w_c = pk2f[r * 16 + 8];
            m_c = bf2f(pk2u[r * 32 + c]);
        }
        den += w;
        acc += w * m;
        s = s2; valid = v2;
    }
    acc += __shfl_xor(acc, 16);
    acc += __shfl_xor(acc, 32);
    den += __shfl_xor(den, 16);
    den += __shfl_xor(den, 32);
    float val = (end > start) ? acc / den : 0.f;
    if (q == 0) outs[wave][c] = val;
    __syncthreads();
    if (tid < 16) {
        float sum = outs[0][tid] + outs[1][tid] + outs[2][tid] + outs[3][tid];
        atomicAdd(ws + OFF_OPART + (blockIdx.x & 63) * 16 + tid, sum);
    }
}

__global__ void final_k(const float* __restrict__ res_b, float* __restrict__ ws, float* __restrict__ out) {
    int c = threadIdx.x;
    if (c < 16) {
        float s = 0.f;
        for (int r = 0; r < 64; ++r) s += ws[OFF_OPART + r * 16 + c];
        out[c] = s * (1.0f / (float)NN) + res_b[c];
    }
}

extern "C" void kernel_launch(void* const* d_in, const int* in_sizes, int n_in,
                              void* d_out, int out_size, void* d_ws, size_t ws_size,
                              hipStream_t stream) {
    const float* x     = (const float*)d_in[0];
    const int*   src   = (const int*)d_in[1];
    const int*   dst   = (const int*)d_in[2];
    // d_in[3] = ntype (unused by reference)
    const int*   etype = (const int*)d_in[4];
    const float* W1    = (const float*)d_in[5];
    const float* al1   = (const float*)d_in[6];
    const float* ar1   = (const float*)d_in[7];
    const float* W2    = (const float*)d_in[8];
    const float* al2   = (const float*)d_in[9];
    const float* ar2   = (const float*)d_in[10];
    const float* res_w = (const float*)d_in[11];
    const float* res_b = (const float*)d_in[12];
    float* ws = (float*)d_ws;
    int* wsi = (int*)d_ws;
    float* out = (float*)d_out;

    hipMemsetAsync((char*)d_ws + (size_t)OFF_BCNT * 4, 0, (size_t)1280 * 4, stream);
    hipLaunchKernelGGL(precompute, dim3(TT), dim3(512), 0, stream, W1, al1, ar1, W2, al2, ar2, ws);
    hipLaunchKernelGGL(fill_cw, dim3(56), dim3(256), 0, stream, W1, W2, res_w, ws);
    hipLaunchKernelGGL(sort_p1, dim3((EE + P1_CHUNK - 1) / P1_CHUNK), dim3(256), 0, stream, src, dst, etype, wsi);
    hipLaunchKernelGGL(sort_p2a, dim3(1), dim3(256), 0, stream, wsi);
    hipLaunchKernelGGL(sort_p2, dim3(NBUCK), dim3(256), 0, stream, wsi);
    hipLaunchKernelGGL(gemm_f, dim3((NN + 63) / 64), dim3(512), 0, stream, x, ws + OFF_CW1, ws);
    hipLaunchKernelGGL(agg1, dim3(NN / 4), dim3(256), 0, stream, wsi, ws);
    hipLaunchKernelGGL(gemm_f2, dim3((NN + 63) / 64), dim3(256), 0, stream, ws + OFF_CW2, ws);
    hipLaunchKernelGGL(agg2, dim3(NN / 4), dim3(256), 0, stream, wsi, ws);
    hipLaunchKernelGGL(final_k, dim3(1), dim3(64), 0, stream, res_b, ws, out);
}